// Round 3
// baseline (102.278 us; speedup 1.0000x reference)
//
#include <hip/hip_runtime.h>

// score[e] = us[src[e]] + vs[dst[e]] + b  where
//   us[n] = dot(user_feats[n], W[0:128]),  vs[m] = dot(item_feats[m], W[128:256])
//
// R4c (compile-fix of R4b: __builtin_nontemporal_* requires clang ext-vector
// types, not HIP_vector_type structs — back to ext_vector_type(2)):
//  - Phase 2: 2 edges/thread (was 4) -> 625 blocks, 2.4 waves/SIMD (was 1.2),
//    better hiding of the cold coalesced index loads.
//  - Non-temporal loads on the streamed-once feature rows and index arrays,
//    non-temporal store on `out`; us/vs keep normal caching (phase-2 gathers
//    want them L2-resident).
//  - Phase 1 structure unchanged (8 row-pairs/wave, 8 independent 1KB loads
//    in flight, all 6252 waves co-resident).
//
// Theory being tested: measured dur_us is ~85us of harness ws-poison fills
// (the only >=42us dispatches in the R3 profile) + ~12us of our kernels vs a
// ~9us HBM traffic floor (51.2MB feats + 2.56MB idx + 1.28MB out).

typedef float f4v __attribute__((ext_vector_type(4)));
typedef float f2v __attribute__((ext_vector_type(2)));
typedef int   i2v __attribute__((ext_vector_type(2)));

__global__ __launch_bounds__(256) void node_score_kernel(
    const float* __restrict__ user_feats,
    const float* __restrict__ item_feats,
    const float* __restrict__ W,
    float* __restrict__ us,
    float* __restrict__ vs,
    int Nu, int Ni)
{
    constexpr int PAIRS = 8;                    // row-pairs per wave (8KB in flight)
    const int lane = threadIdx.x & 63;
    const int wave = (blockIdx.x * (blockDim.x >> 6)) + (threadIdx.x >> 6);

    const int upairs = (Nu + 1) >> 1;
    const int ipairs = (Ni + 1) >> 1;
    const int uwaves = (upairs + PAIRS - 1) / PAIRS;
    const int iwaves = (ipairs + PAIRS - 1) / PAIRS;
    if (wave >= uwaves + iwaves) return;

    const bool is_user = (wave < uwaves);
    const int wv       = is_user ? wave : (wave - uwaves);
    const int N        = is_user ? Nu : Ni;
    const float* feats = is_user ? user_feats : item_feats;
    float* outv        = is_user ? us : vs;

    // W fragment: user half uses W[0:128], item half W[128:256]. Reused by
    // every wave -> normal (cached) load.
    const f4v w = ((const f4v*)W)[(is_user ? 0 : 32) + (lane & 31)];

    const int pair0 = wv * PAIRS;
    const int half  = lane >> 5;                // 0 or 1 within the wave
    const int col   = lane & 31;                // float4 index within a row

    // 8 independent coalesced 16B/lane loads (each pair = 1KB contiguous).
    // Feature rows are touched exactly once -> non-temporal.
    f4v x[PAIRS];
    #pragma unroll
    for (int p = 0; p < PAIRS; ++p) {
        int r = 2 * (pair0 + p) + half;
        if (r >= N) r = N - 1;                  // clamp; result discarded below
        x[p] = __builtin_nontemporal_load(((const f4v*)(feats + (size_t)r * 128)) + col);
    }

    #pragma unroll
    for (int p = 0; p < PAIRS; ++p) {
        float acc = x[p][0] * w[0] + x[p][1] * w[1] + x[p][2] * w[2] + x[p][3] * w[3];
        // Reduce within each 32-lane half.
        #pragma unroll
        for (int off = 16; off > 0; off >>= 1)
            acc += __shfl_down(acc, off, 64);
        if (col == 0) {
            const int row = 2 * (pair0 + p) + half;
            if (row < N) outv[row] = acc;       // cached store: phase 2 re-reads
        }
    }
}

// Phase 2: 2 edges per thread, coalesced int-pair index loads (streamed once
// -> non-temporal), scalar gathers from the 200KB score arrays (L2-resident,
// cached), non-temporal 8B store.
__global__ __launch_bounds__(256) void edge_combine_kernel(
    const int* __restrict__ src,
    const int* __restrict__ dst,
    const float* __restrict__ us,
    const float* __restrict__ vs,
    const float* __restrict__ b,
    float* __restrict__ out,
    int E)
{
    const int t  = blockIdx.x * blockDim.x + threadIdx.x;
    const int E2 = E >> 1;
    const float bias = b[0];

    if (t < E2) {
        const i2v s = __builtin_nontemporal_load(((const i2v*)src) + t);
        const i2v d = __builtin_nontemporal_load(((const i2v*)dst) + t);
        f2v o;
        o[0] = us[s[0]] + vs[d[0]] + bias;
        o[1] = us[s[1]] + vs[d[1]] + bias;
        __builtin_nontemporal_store(o, ((f2v*)out) + t);
    }

    // Tail (E odd).
    const int rem_start = E2 << 1;
    if (t < E - rem_start) {
        const int e = rem_start + t;
        out[e] = us[src[e]] + vs[dst[e]] + bias;
    }
}

extern "C" void kernel_launch(void* const* d_in, const int* in_sizes, int n_in,
                              void* d_out, int out_size, void* d_ws, size_t ws_size,
                              hipStream_t stream) {
    const float* user_feats = (const float*)d_in[0];
    const float* item_feats = (const float*)d_in[1];
    const int*   src_idx    = (const int*)  d_in[2];
    const int*   dst_idx    = (const int*)  d_in[3];
    const float* W          = (const float*)d_in[4];
    const float* b          = (const float*)d_in[5];
    float*       out        = (float*)d_out;

    const int Nu = in_sizes[0] / 128;
    const int Ni = in_sizes[1] / 128;
    const int E  = in_sizes[2];

    float* us = (float*)d_ws;       // Nu floats
    float* vs = us + Nu;            // Ni floats  ((Nu+Ni)*4 B of ws used)

    constexpr int PAIRS = 8;
    const int uwaves  = (((Nu + 1) >> 1) + PAIRS - 1) / PAIRS;
    const int iwaves  = (((Ni + 1) >> 1) + PAIRS - 1) / PAIRS;
    const int waves   = uwaves + iwaves;
    const int blocks1 = (waves * 64 + 255) / 256;
    hipLaunchKernelGGL(node_score_kernel, dim3(blocks1), dim3(256), 0, stream,
                       user_feats, item_feats, W, us, vs, Nu, Ni);

    const int threads2 = (E >> 1) > 0 ? (E >> 1) : E;
    const int blocks2  = (threads2 + 255) / 256;
    hipLaunchKernelGGL(edge_combine_kernel, dim3(blocks2), dim3(256), 0, stream,
                       src_idx, dst_idx, us, vs, b, out, E);
}

// Round 4
// 98.481 us; speedup vs baseline: 1.0385x; 1.0385x over previous
//
#include <hip/hip_runtime.h>

// score[e] = us[src[e]] + vs[dst[e]] + b  where
//   us[n] = dot(user_feats[n], W[0:128]),  vs[m] = dot(item_feats[m], W[128:256])
// Phase 1 streams 51.2 MB coalesced (HBM floor ~8.5us); phase 2 gathers from
// two 200 KB L2-resident score arrays.
//
// R5: exact revert to the measured-best R3 kernel (97.4 us). R4c's changes
// (phase-2 int2 + nt-hints) measured 102.3 us; ~2 us of that was fill-speed
// drift, the rest an unattributable regression at the noise floor. The timed
// window is dominated by 2x ~42.5us harness ws-poison fills (256 MiB each,
// 78% HBM peak); controllable kernel time ~12 us vs ~9 us traffic floor.

__global__ __launch_bounds__(256) void node_score_kernel(
    const float* __restrict__ user_feats,
    const float* __restrict__ item_feats,
    const float* __restrict__ W,
    float* __restrict__ us,
    float* __restrict__ vs,
    int Nu, int Ni)
{
    constexpr int PAIRS = 8;                    // row-pairs per wave (8KB in flight)
    const int lane = threadIdx.x & 63;
    const int wave = (blockIdx.x * (blockDim.x >> 6)) + (threadIdx.x >> 6);

    const int upairs = (Nu + 1) >> 1;
    const int ipairs = (Ni + 1) >> 1;
    const int uwaves = (upairs + PAIRS - 1) / PAIRS;
    const int iwaves = (ipairs + PAIRS - 1) / PAIRS;
    if (wave >= uwaves + iwaves) return;

    const bool is_user = (wave < uwaves);
    const int wv       = is_user ? wave : (wave - uwaves);
    const int N        = is_user ? Nu : Ni;
    const float* feats = is_user ? user_feats : item_feats;
    float* outv        = is_user ? us : vs;

    // W fragment: user half uses W[0:128], item half W[128:256].
    const float4 w = ((const float4*)W)[(is_user ? 0 : 32) + (lane & 31)];

    const int pair0 = wv * PAIRS;
    const int half  = lane >> 5;                // 0 or 1 within the wave
    const int col   = lane & 31;                // float4 index within a row

    // Issue 8 independent coalesced 16B/lane loads (each pair = 1KB contiguous).
    float4 x[PAIRS];
    #pragma unroll
    for (int p = 0; p < PAIRS; ++p) {
        int r = 2 * (pair0 + p) + half;
        if (r >= N) r = N - 1;                  // clamp; result discarded below
        x[p] = ((const float4*)(feats + (size_t)r * 128))[col];
    }

    #pragma unroll
    for (int p = 0; p < PAIRS; ++p) {
        float acc = x[p].x * w.x + x[p].y * w.y + x[p].z * w.z + x[p].w * w.w;
        // Reduce within each 32-lane half.
        #pragma unroll
        for (int off = 16; off > 0; off >>= 1)
            acc += __shfl_down(acc, off, 64);
        if (col == 0) {
            const int row = 2 * (pair0 + p) + half;
            if (row < N) outv[row] = acc;
        }
    }
}

// Phase 2: 4 edges per thread, coalesced int4 index loads, scalar gathers
// from the 200 KB score arrays (L2-resident), float4 store.
__global__ __launch_bounds__(256) void edge_combine_kernel(
    const int* __restrict__ src,
    const int* __restrict__ dst,
    const float* __restrict__ us,
    const float* __restrict__ vs,
    const float* __restrict__ b,
    float* __restrict__ out,
    int E)
{
    const int t  = blockIdx.x * blockDim.x + threadIdx.x;
    const int E4 = E >> 2;
    const float bias = b[0];

    if (t < E4) {
        const int4 s = ((const int4*)src)[t];
        const int4 d = ((const int4*)dst)[t];
        float4 o;
        o.x = us[s.x] + vs[d.x] + bias;
        o.y = us[s.y] + vs[d.y] + bias;
        o.z = us[s.z] + vs[d.z] + bias;
        o.w = us[s.w] + vs[d.w] + bias;
        ((float4*)out)[t] = o;
    }

    // Tail (E % 4 != 0).
    const int rem_start = E4 << 2;
    const int tail = E - rem_start;
    if (t < tail) {
        const int e = rem_start + t;
        out[e] = us[src[e]] + vs[dst[e]] + bias;
    }
}

extern "C" void kernel_launch(void* const* d_in, const int* in_sizes, int n_in,
                              void* d_out, int out_size, void* d_ws, size_t ws_size,
                              hipStream_t stream) {
    const float* user_feats = (const float*)d_in[0];
    const float* item_feats = (const float*)d_in[1];
    const int*   src_idx    = (const int*)  d_in[2];
    const int*   dst_idx    = (const int*)  d_in[3];
    const float* W          = (const float*)d_in[4];
    const float* b          = (const float*)d_in[5];
    float*       out        = (float*)d_out;

    const int Nu = in_sizes[0] / 128;
    const int Ni = in_sizes[1] / 128;
    const int E  = in_sizes[2];

    float* us = (float*)d_ws;       // Nu floats
    float* vs = us + Nu;            // Ni floats  ((Nu+Ni)*4 B of ws used)

    constexpr int PAIRS = 8;
    const int uwaves  = (((Nu + 1) >> 1) + PAIRS - 1) / PAIRS;
    const int iwaves  = (((Ni + 1) >> 1) + PAIRS - 1) / PAIRS;
    const int waves   = uwaves + iwaves;
    const int blocks1 = (waves * 64 + 255) / 256;
    hipLaunchKernelGGL(node_score_kernel, dim3(blocks1), dim3(256), 0, stream,
                       user_feats, item_feats, W, us, vs, Nu, Ni);

    const int threads2 = (E >> 2) > 0 ? (E >> 2) : E;
    const int blocks2  = (threads2 + 255) / 256;
    hipLaunchKernelGGL(edge_combine_kernel, dim3(blocks2), dim3(256), 0, stream,
                       src_idx, dst_idx, us, vs, b, out, E);
}